// Round 7
// baseline (165.945 us; speedup 1.0000x reference)
//
#include <hip/hip_runtime.h>
#include <hip/hip_bf16.h>
#include <stdint.h>

#define IN_F 4096
#define OUT_F 4096
#define NG 32

typedef __attribute__((ext_vector_type(8))) short short8;
typedef __attribute__((ext_vector_type(4))) float floatx4;

#define DQ_BLOCKS 8192   // dequant: 2097152 int32 / 256
#define CV_BLOCKS 2048   // convert: 1024*4096 floats / 8 / 256

// Fused prep: blocks [0, DQ_BLOCKS) dequant W -> bf16 W[n][k], rest convert x.
__global__ __launch_bounds__(256) void prep_kernel(
    const int* __restrict__ wp, const float* __restrict__ scale,
    const int* __restrict__ zero, __hip_bfloat16* __restrict__ Wb,
    const float* __restrict__ x, __hip_bfloat16* __restrict__ xb) {
  int b = blockIdx.x;
  if (b < DQ_BLOCKS) {
    int p = b * 256 + threadIdx.x;                  // 0 .. 2097151
    int row = p >> 9;                               // 512 int32 per output row
    int g = (p >> 4) & 31;                          // 16 int32 per 128-group
    float s = scale[row * NG + g];
    float zs = (float)zero[row * NG + g] * s;
    unsigned v = (unsigned)wp[p];
    union { __hip_bfloat16 h[8]; uint4 u4; } o;
#pragma unroll
    for (int i = 0; i < 8; ++i) {
      int q = (int)((v >> (4 * i)) & 15u);
      q -= (q >= 8) ? 16 : 0;                       // signed 4-bit
      o.h[i] = __float2bfloat16((float)q * s - zs); // (q - zero) * scale
    }
    *(uint4*)(Wb + (size_t)p * 8) = o.u4;
  } else {
    int i = (b - DQ_BLOCKS) * 256 + threadIdx.x;    // 8 floats per thread
    float4 v0 = ((const float4*)x)[i * 2];
    float4 v1 = ((const float4*)x)[i * 2 + 1];
    union { __hip_bfloat16 h[8]; uint4 u4; } o;
    o.h[0] = __float2bfloat16(v0.x); o.h[1] = __float2bfloat16(v0.y);
    o.h[2] = __float2bfloat16(v0.z); o.h[3] = __float2bfloat16(v0.w);
    o.h[4] = __float2bfloat16(v1.x); o.h[5] = __float2bfloat16(v1.y);
    o.h[6] = __float2bfloat16(v1.z); o.h[7] = __float2bfloat16(v1.w);
    ((uint4*)xb)[i] = o.u4;
  }
}

// C[m][n] = sum_k A[m][k] * Bt[n][k]; 128x128 tile / 256 threads, BK=128.
// Grid is 2 blocks/CU, so 64 KB LDS costs no occupancy (m132's regression was
// the 3->2 blocks/CU drop at 4096^3 — doesn't apply here). Barrier count
// halves vs BK=64: the per-iter vmcnt(0)+s_barrier drain is the structural
// stall (m97 ~20%), paid 16x instead of 32x per block.
// Split-K=2: z=0 -> C0 (d_out), z=1 -> C1 (ws partial); reduce adds.
#define BM 128
#define BN 128
#define BK 128
#define SPLITK 2

__global__ __launch_bounds__(256) void gemm_bt(
    const __hip_bfloat16* __restrict__ A, const __hip_bfloat16* __restrict__ Bt,
    float* __restrict__ C0, float* __restrict__ C1, int M, int N, int K) {
  __shared__ short Alds[BM * BK];   // [row][128], unpadded (global_load_lds)
  __shared__ short Blds[BN * BK];   // 32 KB each, 64 KB total

  int t = threadIdx.x;
  int wave = t >> 6, lane = t & 63;
  int wm = (wave >> 1) * 64, wn = (wave & 1) * 64;
  int r = lane & 15, quad = lane >> 4;
  int bm = blockIdx.y * BM, bn = blockIdx.x * BN;
  int kz = blockIdx.z * (K / SPLITK);
  int kend = kz + K / SPLITK;

  floatx4 acc[4][4] = {};

  const __hip_bfloat16* Ag = A + (size_t)bm * K;
  const __hip_bfloat16* Bg = Bt + (size_t)bn * K;

  for (int k0 = kz; k0 < kend; k0 += BK) {
    __syncthreads();  // previous MFMA-phase LDS reads done
    // Stage 32 KB A + 32 KB B: 2048 chunks of 16 B each, 8 A + 8 B per thread.
#pragma unroll
    for (int j = 0; j < 8; ++j) {
      int c = t + 256 * j;            // chunk id in [0, 2048)
      int row = c >> 4, kc = c & 15;  // 16 chunks per 128-elem row
      const __hip_bfloat16* ga = Ag + (size_t)row * K + k0 + kc * 8;
      const __hip_bfloat16* gb = Bg + (size_t)row * K + k0 + kc * 8;
      __builtin_amdgcn_global_load_lds(
          (const __attribute__((address_space(1))) void*)ga,
          (__attribute__((address_space(3))) void*)(&Alds[c * 8]), 16, 0, 0);
      __builtin_amdgcn_global_load_lds(
          (const __attribute__((address_space(1))) void*)gb,
          (__attribute__((address_space(3))) void*)(&Blds[c * 8]), 16, 0, 0);
    }
    __syncthreads();  // implies vmcnt(0): staged tiles visible

#pragma unroll
    for (int ks = 0; ks < 4; ++ks) {
      int kk = ks * 32;
      short8 af[4], bf[4];
#pragma unroll
      for (int mi = 0; mi < 4; ++mi)
        af[mi] = *(const short8*)&Alds[(wm + mi * 16 + r) * BK + kk + quad * 8];
#pragma unroll
      for (int ni = 0; ni < 4; ++ni)
        bf[ni] = *(const short8*)&Blds[(wn + ni * 16 + r) * BK + kk + quad * 8];
#pragma unroll
      for (int mi = 0; mi < 4; ++mi)
#pragma unroll
        for (int ni = 0; ni < 4; ++ni)
          acc[mi][ni] = __builtin_amdgcn_mfma_f32_16x16x32_bf16(
              af[mi], bf[ni], acc[mi][ni], 0, 0, 0);
    }
  }

  // Epilogue: plain stores (no atomics/fences — rounds 3/4 lesson).
  // C/D layout: col = lane&15, row = quad*4 + reg.
  float* Cz = (blockIdx.z == 0) ? C0 : C1;
#pragma unroll
  for (int mi = 0; mi < 4; ++mi) {
#pragma unroll
    for (int ni = 0; ni < 4; ++ni) {
#pragma unroll
      for (int i = 0; i < 4; ++i) {
        int grow = bm + wm + mi * 16 + quad * 4 + i;
        int gcol = bn + wn + ni * 16 + r;
        Cz[(size_t)grow * N + gcol] = acc[mi][ni][i];
      }
    }
  }
}

// out += part, fully coalesced float4.
__global__ __launch_bounds__(256) void reduce_kernel(
    float* __restrict__ out, const float* __restrict__ part) {
  int i = blockIdx.x * 256 + threadIdx.x;
  float4 a = ((const float4*)out)[i];
  float4 b = ((const float4*)part)[i];
  a.x += b.x; a.y += b.y; a.z += b.z; a.w += b.w;
  ((float4*)out)[i] = a;
}

extern "C" void kernel_launch(void* const* d_in, const int* in_sizes, int n_in,
                              void* d_out, int out_size, void* d_ws, size_t ws_size,
                              hipStream_t stream) {
  const float* x = (const float*)d_in[0];
  const int* wp = (const int*)d_in[1];
  const float* wscale = (const float*)d_in[2];
  const int* wzero = (const int*)d_in[3];
  float* out = (float*)d_out;

  int M = in_sizes[0] / IN_F;  // 1024

  size_t wb_bytes = (size_t)OUT_F * IN_F * 2;   // 33.5 MB
  size_t xb_bytes = (size_t)M * IN_F * 2;       // 8.4 MB

  __hip_bfloat16* Wb = (__hip_bfloat16*)d_ws;
  __hip_bfloat16* Xb = (__hip_bfloat16*)((char*)d_ws + wb_bytes);
  float* Cpart = (float*)((char*)d_ws + wb_bytes + xb_bytes);   // 16.8 MB

  prep_kernel<<<DQ_BLOCKS + CV_BLOCKS, 256, 0, stream>>>(wp, wscale, wzero, Wb, x, Xb);

  dim3 grid(OUT_F / BN, M / BM, SPLITK);
  gemm_bt<<<grid, 256, 0, stream>>>(Xb, Wb, out, Cpart, M, OUT_F, IN_F);

  reduce_kernel<<<(M * OUT_F / 4) / 256, 256, 0, stream>>>(out, Cpart);
}